// Round 12
// baseline (885.237 us; speedup 1.0000x reference)
//
#include <hip/hip_runtime.h>

// ---------------------------------------------------------------------------
// Swin shifted-window attention, fused, occupancy-optimized:
// one block = one 8x8 window, 4 waves, each wave owns 2 heads end-to-end.
// LDS 48KB -> 3 blocks/CU. bf16 MFMA 16x16x32, fp32 accumulate, fp32 in/out.
// R12: proj epilogue computes 4 col-tiles then stores 256B-contiguous per
// token (full-line writes) to kill the 3.3x HBM write amplification.
// ---------------------------------------------------------------------------

typedef float f32x4 __attribute__((ext_vector_type(4)));
typedef __bf16 bf16x8 __attribute__((ext_vector_type(8)));
typedef unsigned short u16x4 __attribute__((ext_vector_type(4)));
typedef unsigned short u16x8 __attribute__((ext_vector_type(8)));

#define MFMA16(a, b, c) __builtin_amdgcn_mfma_f32_16x16x32_bf16((a), (b), (c), 0, 0, 0)
#define QSCALE 0.17677669529663687f

__device__ __forceinline__ unsigned short f2bf(float f) {
  union { float f; unsigned u; } v; v.f = f;
  unsigned r = v.u + 0x7FFFu + ((v.u >> 16) & 1u);   // RNE
  return (unsigned short)(r >> 16);
}

__device__ __forceinline__ bf16x8 pack8(float4 f0, float4 f1) {
  union { u16x8 s; bf16x8 v; } u;
  u.s[0] = f2bf(f0.x); u.s[1] = f2bf(f0.y); u.s[2] = f2bf(f0.z); u.s[3] = f2bf(f0.w);
  u.s[4] = f2bf(f1.x); u.s[5] = f2bf(f1.y); u.s[6] = f2bf(f1.z); u.s[7] = f2bf(f1.w);
  return u.v;
}

// Pre-kernel: bf16 weights (q-rows pre-scaled) + masked rel-bias table
// ws layout: [0) wq bf16 196608][196608) wp bf16 65536][524288 B) bias_m f32 131072]
__global__ void prep(const float* __restrict__ qkvW, const float* __restrict__ projW,
                     const float* __restrict__ relTab,
                     unsigned short* __restrict__ wq, unsigned short* __restrict__ wp,
                     float* __restrict__ biasm) {
  int i = blockIdx.x * 256 + threadIdx.x;
  if (i < 196608) {
    float v = qkvW[i];
    if (i < 65536) v *= QSCALE;           // fold q-scale into Wq
    wq[i] = f2bf(v);
  }
  if (i < 65536) wp[i] = f2bf(projW[i]);
  if (i < 131072) {                        // bias_m[var][h][i][j]
    int j = i & 63, ii = (i >> 6) & 63, h = (i >> 12) & 7, var = i >> 15;
    int er = var >> 1, ec = var & 1;
    int ri = ii >> 3, ci = ii & 7, rj = j >> 3, cj = j & 7;
    int ridi = (er ? ((ri < 4) ? 3 : 6) : 0) + (ec ? ((ci < 4) ? 1 : 2) : 0);
    int ridj = (er ? ((rj < 4) ? 3 : 6) : 0) + (ec ? ((cj < 4) ? 1 : 2) : 0);
    float v = relTab[((ri - rj + 7) * 15 + (ci - cj + 7)) * 8 + h];
    if (ridi != ridj) v -= 100.0f;
    biasm[i] = v;
  }
}

// LDS (u16 units):
//  [0,16384)      x window chunk-XOR [32 ch-chunks][64 tok][8]; reused as attn_out
//  [16384,24576)  per-wave scratch 4 x 2048 (Q/K dim-chunked, V tok-chunked, P quarter)
//  [24576,28176)  (fallback only) rel-bias table 1800 f32
template <bool PRE>
__global__ __launch_bounds__(256, 3) void swin_fused(
    const float* __restrict__ x,
    const float* __restrict__ qkvWf, const float* __restrict__ qkvB,
    const float* __restrict__ projWf, const float* __restrict__ projB,
    const float* __restrict__ relTab,
    const unsigned short* __restrict__ qkvWb,
    const unsigned short* __restrict__ projWb,
    const float* __restrict__ biasm,
    float* __restrict__ out) {
  __shared__ unsigned short sm[PRE ? 24576 : 28192];
  const f32x4 Z = {0.0f, 0.0f, 0.0f, 0.0f};

  const int tid = threadIdx.x;
  const int wv = tid >> 6, lane = tid & 63, g = lane >> 4, cl = lane & 15;
  const int blk = blockIdx.x, b = blk >> 8, w = blk & 255, wi = w >> 4, wj = w & 15;
  const bool er = (wi == 15), ec = (wj == 15);
  const int var = (er ? 2 : 0) + (ec ? 1 : 0);

  if (!PRE) {
    float* t = (float*)(sm + 24576);
    for (int i = tid; i < 1800; i += 256) t[i] = relTab[i];
  }

  // ---- stage x: shift-gather fp32->bf16 into chunk-XOR layout ----
  {
    const float* xb = x + (size_t)b * (128 * 128 * 256);
#pragma unroll
    for (int it = 0; it < 8; ++it) {
      int idx = tid + it * 256, t = idx >> 5, ch = idx & 31;
      int hh = (wi * 8 + (t >> 3) + 4) & 127;
      int ww = (wj * 8 + (t & 7) + 4) & 127;
      const float* src = xb + ((((hh << 7) + ww) << 8) + ch * 8);
      float4 f0 = *(const float4*)src;
      float4 f1 = *(const float4*)(src + 4);
      union { u16x8 s; bf16x8 v; } pk;
      pk.s[0] = f2bf(f0.x); pk.s[1] = f2bf(f0.y); pk.s[2] = f2bf(f0.z); pk.s[3] = f2bf(f0.w);
      pk.s[4] = f2bf(f1.x); pk.s[5] = f2bf(f1.y); pk.s[6] = f2bf(f1.z); pk.s[7] = f2bf(f1.w);
      *(u16x8*)(sm + ch * 512 + ((t ^ (2 * (ch & 3))) << 3)) = pk.s;
    }
  }
  __syncthreads();

  unsigned short* scr = sm + 16384 + wv * 2048;
  const int hA = wv * 2, hB = hA + 1;

  // x / attn_out read: row=token, c=channel-chunk -> one b128
  auto ldx = [&](int row, int c) -> bf16x8 {
    return *(const bf16x8*)(sm + c * 512 + ((row ^ (2 * (c & 3))) << 3));
  };
  // [64x256]@[256x32] GEMM -> acc[ct 0..1][rt 0..3]
  auto gemm32 = [&](int colbase, f32x4 (&acc)[2][4]) {
#pragma unroll
    for (int ct = 0; ct < 2; ++ct) {
      const int col = colbase + ct * 16 + cl;
      bf16x8 bw[8];
#pragma unroll
      for (int ks = 0; ks < 8; ++ks) {
        const int off = col * 256 + ks * 32 + g * 8;
        if (PRE) bw[ks] = *(const bf16x8*)(qkvWb + off);
        else {
          float4 a = *(const float4*)(qkvWf + off);
          float4 c2 = *(const float4*)(qkvWf + off + 4);
          bw[ks] = pack8(a, c2);
        }
      }
#pragma unroll
      for (int rt = 0; rt < 4; ++rt) {
        acc[ct][rt] = Z;
#pragma unroll
        for (int ks = 0; ks < 8; ++ks)
          acc[ct][rt] = MFMA16(ldx(rt * 16 + cl, ks * 4 + g), bw[ks], acc[ct][rt]);
      }
    }
  };
  // Q/K epilogue -> scratch dim-chunked [cQ=dim>>3][tok ^ 2(cQ&3)][dim&7]
  auto epiQK = [&](f32x4 (&acc)[2][4], int colbase, bool isQ) {
#pragma unroll
    for (int ct = 0; ct < 2; ++ct) {
      const int col = colbase + ct * 16 + cl;
      float bs = qkvB[col]; if (isQ) bs *= QSCALE;
      const int cQ = 2 * ct + (cl >> 3), Xr = 2 * (cQ & 3);
#pragma unroll
      for (int rt = 0; rt < 4; ++rt)
#pragma unroll
        for (int r = 0; r < 4; ++r) {
          float v = acc[ct][rt][r];
          if (!PRE && isQ) v *= QSCALE;
          scr[cQ * 512 + (((rt * 16 + 4 * g + r) ^ Xr) << 3) + (cl & 7)] = f2bf(v + bs);
        }
    }
  };
  auto ldQK = [&](int it) -> bf16x8 {   // A/B frag: row=it*16+cl, dims 8g..8g+7
    return *(const bf16x8*)(scr + g * 512 + (((it * 16 + cl) ^ (2 * g)) << 3));
  };
  // V epilogue -> scratch tok-chunked [cV=tok>>3][dim ^ 2(cV&3)][tok&7] (u16x4 packs)
  auto epiV = [&](f32x4 (&acc)[2][4], int colbase) {
#pragma unroll
    for (int ct = 0; ct < 2; ++ct) {
      const int col = colbase + ct * 16 + cl;
      const float bs = qkvB[col];
#pragma unroll
      for (int rt = 0; rt < 4; ++rt) {
        const int cV = 2 * rt + (g >> 1);
        const int pos = (ct * 16 + cl) ^ (2 * (cV & 3));
        u16x4 pk;
#pragma unroll
        for (int r = 0; r < 4; ++r) pk[r] = f2bf(acc[ct][rt][r] + bs);
        *(u16x4*)(scr + cV * 256 + pos * 8 + 4 * (g & 1)) = pk;
      }
    }
  };
  auto ldV = [&](int ks, int dt) -> bf16x8 {  // B frag: k=tok 32ks+8g.., col=dim 16dt+cl
    const int c = ks * 4 + g;
    return *(const bf16x8*)(scr + c * 256 + (((dt * 16 + cl) ^ (2 * (c & 3))) << 3));
  };
  // attention for one head: swapped QK^T, quarter-wise softmax, P via scratch, PV
  auto attnHead = [&](int h, bf16x8 (&aq)[4], bf16x8 (&ak)[4], bf16x8 (&bv)[2][2],
                      f32x4 (&o)[4][2]) {
    bf16x8 ap[4][2];
#pragma unroll
    for (int qt = 0; qt < 4; ++qt) {
      f32x4 s4[4];
#pragma unroll
      for (int jt = 0; jt < 4; ++jt) s4[jt] = MFMA16(ak[jt], aq[qt], Z);
      const int i = qt * 16 + cl;
      if (PRE) {
        const float* bp = biasm + (((var * 8 + h) * 64 + i) << 6) + g * 4;
#pragma unroll
        for (int jt = 0; jt < 4; ++jt) s4[jt] += *(const f32x4*)(bp + jt * 16);
      } else {
        const float* tab = (const float*)(sm + 24576);
        const int ri = i >> 3, ci = i & 7;
        const int ridi = (er ? ((ri < 4) ? 3 : 6) : 0) + (ec ? ((ci < 4) ? 1 : 2) : 0);
#pragma unroll
        for (int jt = 0; jt < 4; ++jt)
#pragma unroll
          for (int r = 0; r < 4; ++r) {
            const int j = jt * 16 + 4 * g + r, rj = j >> 3, cj = j & 7;
            const int ridj = (er ? ((rj < 4) ? 3 : 6) : 0) + (ec ? ((cj < 4) ? 1 : 2) : 0);
            float v2 = s4[jt][r] + tab[((ri - rj + 7) * 15 + (ci - cj + 7)) * 8 + h];
            if (ridi != ridj) v2 -= 100.0f;
            s4[jt][r] = v2;
          }
      }
      float mx = -1e30f;
#pragma unroll
      for (int jt = 0; jt < 4; ++jt)
#pragma unroll
        for (int r = 0; r < 4; ++r) mx = fmaxf(mx, s4[jt][r]);
      mx = fmaxf(mx, __shfl_xor(mx, 16));
      mx = fmaxf(mx, __shfl_xor(mx, 32));
      float sum = 0.0f;
#pragma unroll
      for (int jt = 0; jt < 4; ++jt)
#pragma unroll
        for (int r = 0; r < 4; ++r) {
          float e = __expf(s4[jt][r] - mx);
          s4[jt][r] = e; sum += e;
        }
      sum += __shfl_xor(sum, 16);
      sum += __shfl_xor(sum, 32);
      const float rs = 1.0f / sum;
      // P quarter -> scratch [cP=j>>3][row(i&15) ^ 2(cP&3)][j&7]
#pragma unroll
      for (int jt = 0; jt < 4; ++jt) {
        const int cP = 2 * jt + (g >> 1);
        const int pos = cl ^ (2 * (cP & 3));
        u16x4 pk;
#pragma unroll
        for (int r = 0; r < 4; ++r) pk[r] = f2bf(s4[jt][r] * rs);
        *(u16x4*)(scr + cP * 128 + pos * 8 + 4 * (g & 1)) = pk;
      }
#pragma unroll
      for (int ks = 0; ks < 2; ++ks)
        ap[qt][ks] = *(const bf16x8*)(scr + (ks * 4 + g) * 128 + ((cl ^ (2 * g)) << 3));
    }
#pragma unroll
    for (int it = 0; it < 4; ++it)
#pragma unroll
      for (int dt = 0; dt < 2; ++dt) {
        o[it][dt] = Z;
#pragma unroll
        for (int ks = 0; ks < 2; ++ks)
          o[it][dt] = MFMA16(ap[it][ks], bv[ks][dt], o[it][dt]);
      }
  };
  auto writeO = [&](int h, f32x4 (&o)[4][2]) {
#pragma unroll
    for (int it = 0; it < 4; ++it)
#pragma unroll
      for (int dt = 0; dt < 2; ++dt) {
        const int d = h * 32 + dt * 16 + cl;
        const int cA = d >> 3, Xr = 2 * (cA & 3);
#pragma unroll
        for (int r = 0; r < 4; ++r)
          sm[cA * 512 + (((it * 16 + 4 * g + r) ^ Xr) << 3) + (d & 7)] = f2bf(o[it][dt][r]);
      }
  };

  // ---- per-wave QKV (heads A,B), head-A attention overlapped before VB ----
  bf16x8 aqA[4], akA[4], bvA[2][2], aqB[4], akB[4], bvB[2][2];
  {
    f32x4 acc[2][4];
    gemm32(hA * 32, acc);        epiQK(acc, hA * 32, true);
#pragma unroll
    for (int i2 = 0; i2 < 4; ++i2) aqA[i2] = ldQK(i2);
    gemm32(256 + hA * 32, acc);  epiQK(acc, 256 + hA * 32, false);
#pragma unroll
    for (int i2 = 0; i2 < 4; ++i2) akA[i2] = ldQK(i2);
    gemm32(512 + hA * 32, acc);  epiV(acc, 512 + hA * 32);
#pragma unroll
    for (int ks = 0; ks < 2; ++ks)
#pragma unroll
      for (int dt = 0; dt < 2; ++dt) bvA[ks][dt] = ldV(ks, dt);
    gemm32(hB * 32, acc);        epiQK(acc, hB * 32, true);
#pragma unroll
    for (int i2 = 0; i2 < 4; ++i2) aqB[i2] = ldQK(i2);
    gemm32(256 + hB * 32, acc);  epiQK(acc, 256 + hB * 32, false);
#pragma unroll
    for (int i2 = 0; i2 < 4; ++i2) akB[i2] = ldQK(i2);
  }
  f32x4 oA[4][2];
  attnHead(hA, aqA, akA, bvA, oA);       // uses scr for P; x still intact
  {
    f32x4 acc[2][4];
    gemm32(512 + hB * 32, acc);  epiV(acc, 512 + hB * 32);
#pragma unroll
    for (int ks = 0; ks < 2; ++ks)
#pragma unroll
      for (int dt = 0; dt < 2; ++dt) bvB[ks][dt] = ldV(ks, dt);
  }
  __syncthreads();                        // all x reads done -> region becomes attn_out
  writeO(hA, oA);
  {
    f32x4 oB[4][2];
    attnHead(hB, aqB, akB, bvB, oB);
    writeO(hB, oB);
  }
  __syncthreads();

  // ---- proj GEMM [64x256]@[256x256] + bias ----
  // R12: compute this wave's 4 col-tiles first, then store 64 consecutive
  // channels (256B) per token back-to-back -> full-128B-line HBM writes.
  auto projGemm = [&](int ct, f32x4 (&acc)[4]) {
    const int col = (wv * 4 + ct) * 16 + cl;
    bf16x8 bw[8];
#pragma unroll
    for (int ks = 0; ks < 8; ++ks) {
      const int off = col * 256 + ks * 32 + g * 8;
      if (PRE) bw[ks] = *(const bf16x8*)(projWb + off);
      else {
        float4 a = *(const float4*)(projWf + off);
        float4 c2 = *(const float4*)(projWf + off + 4);
        bw[ks] = pack8(a, c2);
      }
    }
#pragma unroll
    for (int rt = 0; rt < 4; ++rt) {
      acc[rt] = Z;
#pragma unroll
      for (int ks = 0; ks < 8; ++ks)
        acc[rt] = MFMA16(ldx(rt * 16 + cl, ks * 4 + g), bw[ks], acc[rt]);
    }
  };
  {
    f32x4 p0[4], p1[4], p2[4], p3[4];
    projGemm(0, p0); projGemm(1, p1); projGemm(2, p2); projGemm(3, p3);
    const int cbase = wv * 64 + cl;
    const float b0 = projB[cbase];
    const float b1 = projB[cbase + 16];
    const float b2 = projB[cbase + 32];
    const float b3 = projB[cbase + 48];
#pragma unroll
    for (int rt = 0; rt < 4; ++rt)
#pragma unroll
      for (int r = 0; r < 4; ++r) {
        const int t = rt * 16 + 4 * g + r;
        const int ho = (wi * 8 + (t >> 3) + 4) & 127;
        const int wo = (wj * 8 + (t & 7) + 4) & 127;
        float* po = out + (((size_t)((b << 14) + (ho << 7) + wo)) << 8) + cbase;
        po[0]  = p0[rt][r] + b0;
        po[16] = p1[rt][r] + b1;
        po[32] = p2[rt][r] + b2;
        po[48] = p3[rt][r] + b3;
      }
  }
}

extern "C" void kernel_launch(void* const* d_in, const int* in_sizes, int n_in,
                              void* d_out, int out_size, void* d_ws, size_t ws_size,
                              hipStream_t stream) {
  const float* x     = (const float*)d_in[0];
  const float* qkvW  = (const float*)d_in[1];
  const float* qkvB  = (const float*)d_in[2];
  const float* projW = (const float*)d_in[3];
  const float* projB = (const float*)d_in[4];
  const float* tab   = (const float*)d_in[5];
  float* out = (float*)d_out;

  const size_t needW = (size_t)(196608 + 65536) * sizeof(unsigned short);   // 524288
  const size_t need  = needW + (size_t)131072 * sizeof(float);              // 1 MiB
  if (ws_size >= need) {
    unsigned short* wq = (unsigned short*)d_ws;
    unsigned short* wp = wq + 196608;
    float* biasm = (float*)((char*)d_ws + needW);
    prep<<<dim3(768), dim3(256), 0, stream>>>(qkvW, projW, tab, wq, wp, biasm);
    swin_fused<true><<<dim3(4096), dim3(256), 0, stream>>>(
        x, qkvW, qkvB, projW, projB, tab, wq, wp, biasm, out);
  } else {
    swin_fused<false><<<dim3(4096), dim3(256), 0, stream>>>(
        x, qkvW, qkvB, projW, projB, tab, nullptr, nullptr, nullptr, out);
  }
}